// Round 1
// baseline (1414.777 us; speedup 1.0000x reference)
//
#include <hip/hip_runtime.h>
#include <hip/hip_bf16.h>

// MambaLayer fused pipeline, fp32.
// ws layout (floats): xz[64*384*512] | out_sum[64*512*192] | xdbl[3*64*512*40] | csum[96]
// total ~91.2 MB.

#define DEV __device__ __forceinline__

DEV float fsigmoid(float x) { return 1.f / (1.f + __expf(-x)); }
DEV float fsilu(float x) { return x * fsigmoid(x); }

// position m in the permuted (scan) domain -> source index in original L domain.
// Same map is used for gathering xz and scattering y (verified: both are sigma).
DEV int sigma(int v, int m) {
  if (v == 0) return m;
  if (v == 1) return 511 - m;
  return ((m & 7) << 6) | (m >> 3);   // v3 inter-slice: m=i*8+j -> j*64+i
}

struct ScanParams {
  const float* cw[3]; const float* cb[3]; const float* xp[3];
  const float* dtw[3]; const float* dtb[3]; const float* al[3]; const float* dp[3];
};

// ---------------- K1: window_partition + LayerNorm + in_proj GEMM -> xz (b,e,l)
__global__ __launch_bounds__(256) void k1_ln_inproj(const float* __restrict__ x,
    const float* __restrict__ lnw, const float* __restrict__ lnb,
    const float* __restrict__ wip, float* __restrict__ xz) {
  __shared__ float xt[64 * 97];       // [token][chan], pad 97 -> conflict-free both ways
  __shared__ float mu_s[64], rs_s[64];
  const int tid = threadIdx.x;
  const int t0 = blockIdx.x * 64;     // 64 tokens per block, 512 blocks
  const int b = t0 >> 9, l0 = t0 & 511;
  const int hb = b >> 4, wb = (b >> 2) & 3, db = b & 3;
  for (int m = tid; m < 96 * 64; m += 256) {
    int c = m >> 6, tt = m & 63;
    int l = l0 + tt;
    int i = l >> 6, j = (l >> 3) & 7, k = l & 7;
    xt[tt * 97 + c] = x[c * 32768 + (hb * 8 + i) * 1024 + (wb * 8 + j) * 32 + (db * 8 + k)];
  }
  __syncthreads();
  if (tid < 64) {
    float s = 0.f;
    for (int c = 0; c < 96; ++c) s += xt[tid * 97 + c];
    float mu = s * (1.f / 96.f);
    float s2 = 0.f;
    for (int c = 0; c < 96; ++c) { float dv = xt[tid * 97 + c] - mu; s2 = fmaf(dv, dv, s2); }
    mu_s[tid] = mu;
    rs_s[tid] = rsqrtf(s2 * (1.f / 96.f) + 1e-5f);
  }
  __syncthreads();
  for (int m = tid; m < 96 * 64; m += 256) {
    int c = m >> 6, tt = m & 63;
    xt[tt * 97 + c] = (xt[tt * 97 + c] - mu_s[tt]) * rs_s[tt] * lnw[c] + lnb[c];
  }
  __syncthreads();
  const int tt = tid & 63;
  const int g = __builtin_amdgcn_readfirstlane(tid >> 6);  // wave id 0..3 (uniform)
  const int l = l0 + tt;
  const size_t obase = (size_t)b * 384 * 512 + l;
  for (int eb = 0; eb < 12; ++eb) {
    const int e0 = g * 96 + eb * 8;
    float acc[8];
#pragma unroll
    for (int q = 0; q < 8; ++q) acc[q] = 0.f;
    for (int c = 0; c < 96; ++c) {
      float xv = xt[tt * 97 + c];
#pragma unroll
      for (int q = 0; q < 8; ++q) acc[q] = fmaf(xv, wip[(e0 + q) * 96 + c], acc[q]);
    }
#pragma unroll
    for (int q = 0; q < 8; ++q) xz[obase + (size_t)(e0 + q) * 512] = acc[q];
  }
}

// ---------------- K2: causal conv1d + silu + x_dbl projection -> xdbl (v,b,l,slot40)
// slot layout per token: dt[0..5], (pad 6..7), B[8..23], C[24..39]  (16B-aligned B/C)
__global__ __launch_bounds__(256) void k2_conv_xdbl(const float* __restrict__ xz,
    ScanParams p, float* __restrict__ xdbl) {
  __shared__ float xc[192 * 65];
  const int ci = blockIdx.x, b = blockIdx.y, v = blockIdx.z;
  const int l0 = ci * 64;
  const float* cw = p.cw[v]; const float* cb = p.cb[v]; const float* xp = p.xp[v];
  const int tid = threadIdx.x;
  const float* rowx_base = xz + (size_t)b * 384 * 512;
  for (int m = tid; m < 192 * 64; m += 256) {
    int dd = m >> 6, l = m & 63;
    const float* rowx = rowx_base + (size_t)dd * 512;
    float acc = cb[dd];
#pragma unroll
    for (int j = 0; j < 4; ++j) {
      int mm = l0 + l - 3 + j;
      if (mm >= 0) acc = fmaf(cw[dd * 4 + j], rowx[sigma(v, mm)], acc);
    }
    xc[dd * 65 + l] = fsilu(acc);
  }
  __syncthreads();
  const int lane = tid & 63;
  const int w = __builtin_amdgcn_readfirstlane(tid >> 6);  // wave handles 10 r's
  float acc[10];
#pragma unroll
  for (int rr = 0; rr < 10; ++rr) acc[rr] = 0.f;
  for (int dd = 0; dd < 192; ++dd) {
    float xv = xc[dd * 65 + lane];
#pragma unroll
    for (int rr = 0; rr < 10; ++rr) {
      int r = w * 10 + rr;
      if (r < 38) acc[rr] = fmaf(xv, xp[r * 192 + dd], acc[rr]);
    }
  }
  const size_t base = (((size_t)(v * 64 + b)) * 512 + (l0 + lane)) * 40;
#pragma unroll
  for (int rr = 0; rr < 10; ++rr) {
    int r = w * 10 + rr;
    if (r < 38) xdbl[base + (r < 6 ? r : r + 2)] = acc[rr];
  }
}

// ---------------- K3: selective scan. block = (b, v); thread d<192 owns h[16].
__global__ __launch_bounds__(256) void k3_scan(const float* __restrict__ xz,
    const float* __restrict__ xdbl, ScanParams p, float* __restrict__ osum) {
  __shared__ __align__(16) float xs[192 * 33];
  __shared__ __align__(16) float zs[192 * 33];
  __shared__ __align__(16) float xd[32 * 40];
  const int bv = blockIdx.x;
  const int v = bv % 3, b = bv / 3;
  const float* cw = p.cw[v]; const float* cb = p.cb[v];
  const float* dtw = p.dtw[v]; const float* dtb = p.dtb[v];
  const float* al = p.al[v]; const float* dp = p.dp[v];
  const int tid = threadIdx.x;
  float A2[16], h[16], dtwr[6], dtbd = 0.f, Dpd = 0.f;
  if (tid < 192) {
#pragma unroll
    for (int s = 0; s < 16; ++s) { A2[s] = -__expf(al[tid * 16 + s]); h[s] = 0.f; }
#pragma unroll
    for (int r = 0; r < 6; ++r) dtwr[r] = dtw[tid * 6 + r];
    dtbd = dtb[tid]; Dpd = dp[tid];
  }
  const float* rowx_base = xz + (size_t)b * 384 * 512;
  const size_t xdbase = (((size_t)(v * 64 + b)) * 512) * 40;
  for (int ci = 0; ci < 16; ++ci) {
    const int l0 = ci * 32;
    __syncthreads();
    // stage conv'd u and z for this 32-step chunk
    for (int m = tid; m < 192 * 32; m += 256) {
      int dd = m >> 5, l = m & 31;
      const float* rowx = rowx_base + (size_t)dd * 512;
      const float* rowz = rowx_base + (size_t)(192 + dd) * 512;
      float acc = cb[dd];
#pragma unroll
      for (int j = 0; j < 4; ++j) {
        int mm = l0 + l - 3 + j;
        if (mm >= 0) acc = fmaf(cw[dd * 4 + j], rowx[sigma(v, mm)], acc);
      }
      xs[dd * 33 + l] = fsilu(acc);
      zs[dd * 33 + l] = rowz[sigma(v, l0 + l)];
    }
    for (int m = tid; m < 32 * 40; m += 256) xd[m] = xdbl[xdbase + (size_t)l0 * 40 + m];
    __syncthreads();
    if (tid < 192) {
      for (int l = 0; l < 32; ++l) {
        const float* row = xd + l * 40;
        float dtv = dtbd;
#pragma unroll
        for (int r = 0; r < 6; ++r) dtv = fmaf(row[r], dtwr[r], dtv);
        float delta = (dtv > 15.f) ? dtv : __logf(1.f + __expf(dtv));
        float Bv[16], Cv[16];
#pragma unroll
        for (int q = 0; q < 4; ++q) {
          float4 tb = ((const float4*)(row + 8))[q];
          float4 tc = ((const float4*)(row + 24))[q];
          Bv[4 * q] = tb.x; Bv[4 * q + 1] = tb.y; Bv[4 * q + 2] = tb.z; Bv[4 * q + 3] = tb.w;
          Cv[4 * q] = tc.x; Cv[4 * q + 1] = tc.y; Cv[4 * q + 2] = tc.z; Cv[4 * q + 3] = tc.w;
        }
        float u = xs[tid * 33 + l];
        float du = delta * u;
        float y = 0.f;
#pragma unroll
        for (int s = 0; s < 16; ++s) {
          h[s] = fmaf(h[s], __expf(delta * A2[s]), du * Bv[s]);
          y = fmaf(h[s], Cv[s], y);
        }
        float zv = zs[tid * 33 + l];
        float res = (y + Dpd * u) * fsilu(zv);
        unsafeAtomicAdd(&osum[((size_t)b * 512 + sigma(v, l0 + l)) * 192 + tid], res);
      }
    }
  }
}

// ---------------- K4: out_proj + window_reverse + residual + channel sums
__global__ __launch_bounds__(256) void k4_outproj(const float* __restrict__ osum,
    const float* __restrict__ wop, const float* __restrict__ x,
    float* __restrict__ out, float* __restrict__ csum) {
  __shared__ float yt[64 * 193];
  const int tid = threadIdx.x;
  const int t0 = blockIdx.x * 64;
  const int b = t0 >> 9, l0 = t0 & 511;
  for (int m = tid; m < 64 * 192; m += 256) {
    int tt = m / 192, dd = m - tt * 192;
    yt[tt * 193 + dd] = osum[((size_t)b * 512 + l0 + tt) * 192 + dd];
  }
  __syncthreads();
  const int tt = tid & 63;
  const int g = __builtin_amdgcn_readfirstlane(tid >> 6);
  const int l = l0 + tt;
  const int hb = b >> 4, wb = (b >> 2) & 3, db = b & 3;
  const int i = l >> 6, j = (l >> 3) & 7, k = l & 7;
  const int sp = (hb * 8 + i) * 1024 + (wb * 8 + j) * 32 + (db * 8 + k);
  for (int eb = 0; eb < 3; ++eb) {
    const int e0 = g * 24 + eb * 8;
    float acc[8];
#pragma unroll
    for (int q = 0; q < 8; ++q) acc[q] = 0.f;
    for (int dd = 0; dd < 192; ++dd) {
      float yv = yt[tt * 193 + dd];
#pragma unroll
      for (int q = 0; q < 8; ++q) acc[q] = fmaf(yv, wop[(e0 + q) * 192 + dd], acc[q]);
    }
#pragma unroll
    for (int q = 0; q < 8; ++q) {
      const int c = e0 + q;
      float val = acc[q] + x[c * 32768 + sp];
      out[c * 32768 + sp] = val;
      float vs = val;
#pragma unroll
      for (int off = 32; off >= 1; off >>= 1) vs += __shfl_xor(vs, off);
      if (tt == 0) unsafeAtomicAdd(&csum[c], vs);
    }
  }
}

// ---------------- K5: ECA gate (k=3 conv over channel means + sigmoid), in-place scale
__global__ __launch_bounds__(256) void k5_eca(float* __restrict__ out,
    const float* __restrict__ csum, const float* __restrict__ ew) {
  const int idx = blockIdx.x * 256 + threadIdx.x;   // float4 index, 786432 total
  const int c = (idx * 4) >> 15;                    // 32768 elems per channel, /4-aligned
  const float inv = 1.f / 32768.f;
  float m0 = csum[c] * inv;
  float mm = (c > 0) ? csum[c - 1] * inv : 0.f;
  float mp = (c < 95) ? csum[c + 1] * inv : 0.f;
  float gate = fsigmoid(ew[0] * mm + ew[1] * m0 + ew[2] * mp);
  float4 vv = ((const float4*)out)[idx];
  vv.x *= gate; vv.y *= gate; vv.z *= gate; vv.w *= gate;
  ((float4*)out)[idx] = vv;
}

extern "C" void kernel_launch(void* const* d_in, const int* in_sizes, int n_in,
                              void* d_out, int out_size, void* d_ws, size_t ws_size,
                              hipStream_t stream) {
  const float* x   = (const float*)d_in[0];
  const float* lnw = (const float*)d_in[1];
  const float* lnb = (const float*)d_in[2];
  const float* wip = (const float*)d_in[3];
  const float* wop = (const float*)d_in[4];
  const float* ew  = (const float*)d_in[5];
  ScanParams p;
  for (int v = 0; v < 3; ++v) {
    const int base = 6 + 7 * v;   // f, b, s param groups in setup_inputs dict order
    p.cw[v]  = (const float*)d_in[base + 0];
    p.cb[v]  = (const float*)d_in[base + 1];
    p.xp[v]  = (const float*)d_in[base + 2];
    p.dtw[v] = (const float*)d_in[base + 3];
    p.dtb[v] = (const float*)d_in[base + 4];
    p.al[v]  = (const float*)d_in[base + 5];
    p.dp[v]  = (const float*)d_in[base + 6];
  }
  float* ws   = (float*)d_ws;
  float* xz   = ws;                       // 12,582,912 floats
  float* osum = ws + 12582912;            //  6,291,456 floats
  float* xdbl = ws + 18874368;            //  3,932,160 floats
  float* csum = ws + 22806528;            //         96 floats
  float* outf = (float*)d_out;

  hipMemsetAsync(osum, 0, (size_t)6291456 * 4, stream);
  hipMemsetAsync(csum, 0, 96 * 4, stream);
  k1_ln_inproj<<<512, 256, 0, stream>>>(x, lnw, lnb, wip, xz);
  k2_conv_xdbl<<<dim3(8, 64, 3), 256, 0, stream>>>(xz, p, xdbl);
  k3_scan<<<192, 256, 0, stream>>>(xz, xdbl, p, osum);
  k4_outproj<<<512, 256, 0, stream>>>(osum, wop, x, outf, csum);
  k5_eca<<<3072, 256, 0, stream>>>(outf, csum, ew);
}

// Round 2
// 1047.323 us; speedup vs baseline: 1.3509x; 1.3509x over previous
//
#include <hip/hip_runtime.h>
#include <hip/hip_bf16.h>

// MambaLayer fused pipeline, fp32, chunk-parallel selective scan.
// ws layout (floats):
//   xz   [64*384*512]            = 12,582,912
//   osum [64*512*192]            =  6,291,456
//   xdbl [3*64*512*40]           =  3,932,160
//   csum [96]
//   hend [3*64*8*192*16]         =  2,359,296   (after k3b: holds Hin per chunk)
//   pA   [3*64*8*192*16]         =  2,359,296
// total ~110 MB.

#define DEV __device__ __forceinline__
#define NCH 8           // scan chunks (L=512 -> 64 steps per chunk)

DEV float fsigmoid(float x) { return 1.f / (1.f + __expf(-x)); }
DEV float fsilu(float x) { return x * fsigmoid(x); }

// position m in the permuted (scan) domain -> source index in original L domain.
DEV int sigma(int v, int m) {
  if (v == 0) return m;
  if (v == 1) return 511 - m;
  return ((m & 7) << 6) | (m >> 3);   // v3 inter-slice: m=i*8+j -> j*64+i
}

struct ScanParams {
  const float* cw[3]; const float* cb[3]; const float* xp[3];
  const float* dtw[3]; const float* dtb[3]; const float* al[3]; const float* dp[3];
};

// ---------------- K1: window_partition + LayerNorm + in_proj GEMM -> xz (b,e,l)
__global__ __launch_bounds__(256) void k1_ln_inproj(const float* __restrict__ x,
    const float* __restrict__ lnw, const float* __restrict__ lnb,
    const float* __restrict__ wip, float* __restrict__ xz) {
  __shared__ float xt[64 * 97];       // [token][chan]
  __shared__ float wt[96 * 68];       // [chan][e_local], pad 68 keeps 16B align for float4
  __shared__ float mu_s[64], rs_s[64];
  const int tid = threadIdx.x;
  const int t0 = blockIdx.x * 64;     // 64 tokens per block, 512 blocks
  const int b = t0 >> 9, l0 = t0 & 511;
  const int hb = b >> 4, wb = (b >> 2) & 3, db = b & 3;
  for (int m = tid; m < 96 * 64; m += 256) {
    int c = m >> 6, tt = m & 63;
    int l = l0 + tt;
    int i = l >> 6, j = (l >> 3) & 7, k = l & 7;
    xt[tt * 97 + c] = x[c * 32768 + (hb * 8 + i) * 1024 + (wb * 8 + j) * 32 + (db * 8 + k)];
  }
  __syncthreads();
  if (tid < 64) {
    float s = 0.f;
    for (int c = 0; c < 96; ++c) s += xt[tid * 97 + c];
    float mu = s * (1.f / 96.f);
    float s2 = 0.f;
    for (int c = 0; c < 96; ++c) { float dv = xt[tid * 97 + c] - mu; s2 = fmaf(dv, dv, s2); }
    mu_s[tid] = mu;
    rs_s[tid] = rsqrtf(s2 * (1.f / 96.f) + 1e-5f);
  }
  __syncthreads();
  for (int m = tid; m < 96 * 64; m += 256) {
    int c = m >> 6, tt = m & 63;
    xt[tt * 97 + c] = (xt[tt * 97 + c] - mu_s[tt]) * rs_s[tt] * lnw[c] + lnb[c];
  }
  __syncthreads();
  // GEMM: 64 tokens x 384 outputs, e-tiles of 64. thread = 4 tokens x 4 e.
  const int t0l = (tid & 15) * 4;     // token-minor for coalesced stores
  const int e0 = (tid >> 4) * 4;
  const size_t obase = (size_t)b * 384 * 512;
  for (int et = 0; et < 6; ++et) {
    for (int m = tid; m < 64 * 96; m += 256) {
      int e_l = m / 96, c = m - e_l * 96;
      wt[c * 68 + e_l] = wip[(et * 64 + e_l) * 96 + c];
    }
    __syncthreads();
    float acc[4][4];
#pragma unroll
    for (int j = 0; j < 4; ++j)
#pragma unroll
      for (int i = 0; i < 4; ++i) acc[j][i] = 0.f;
    for (int c = 0; c < 96; ++c) {
      float4 bv = *(const float4*)&wt[c * 68 + e0];
      float a0 = xt[(t0l + 0) * 97 + c], a1 = xt[(t0l + 1) * 97 + c];
      float a2 = xt[(t0l + 2) * 97 + c], a3 = xt[(t0l + 3) * 97 + c];
      acc[0][0] = fmaf(a0, bv.x, acc[0][0]); acc[0][1] = fmaf(a0, bv.y, acc[0][1]);
      acc[0][2] = fmaf(a0, bv.z, acc[0][2]); acc[0][3] = fmaf(a0, bv.w, acc[0][3]);
      acc[1][0] = fmaf(a1, bv.x, acc[1][0]); acc[1][1] = fmaf(a1, bv.y, acc[1][1]);
      acc[1][2] = fmaf(a1, bv.z, acc[1][2]); acc[1][3] = fmaf(a1, bv.w, acc[1][3]);
      acc[2][0] = fmaf(a2, bv.x, acc[2][0]); acc[2][1] = fmaf(a2, bv.y, acc[2][1]);
      acc[2][2] = fmaf(a2, bv.z, acc[2][2]); acc[2][3] = fmaf(a2, bv.w, acc[2][3]);
      acc[3][0] = fmaf(a3, bv.x, acc[3][0]); acc[3][1] = fmaf(a3, bv.y, acc[3][1]);
      acc[3][2] = fmaf(a3, bv.z, acc[3][2]); acc[3][3] = fmaf(a3, bv.w, acc[3][3]);
    }
#pragma unroll
    for (int i = 0; i < 4; ++i) {
      float4 o = make_float4(acc[0][i], acc[1][i], acc[2][i], acc[3][i]);
      *(float4*)&xz[obase + (size_t)(et * 64 + e0 + i) * 512 + (l0 + t0l)] = o;
    }
    __syncthreads();
  }
}

// ---------------- K2: causal conv1d + silu + x_dbl projection -> xdbl (v,b,l,slot40)
// slot layout per token: dt[0..5], (pad 6..7), B[8..23], C[24..39]
__global__ __launch_bounds__(256) void k2_conv_xdbl(const float* __restrict__ xz,
    ScanParams p, float* __restrict__ xdbl) {
  __shared__ float xc[192 * 65];
  __shared__ float xp_s[38 * 192];
  const int ci = blockIdx.x, b = blockIdx.y, v = blockIdx.z;
  const int l0 = ci * 64;
  const float* cw = p.cw[v]; const float* cb = p.cb[v]; const float* xp = p.xp[v];
  const int tid = threadIdx.x;
  const float* rowx_base = xz + (size_t)b * 384 * 512;
  for (int m = tid; m < 38 * 192; m += 256) xp_s[m] = xp[m];
  for (int m = tid; m < 192 * 64; m += 256) {
    int dd = m >> 6, l = m & 63;
    const float* rowx = rowx_base + (size_t)dd * 512;
    float acc = cb[dd];
#pragma unroll
    for (int j = 0; j < 4; ++j) {
      int mm = l0 + l - 3 + j;
      if (mm >= 0) acc = fmaf(cw[dd * 4 + j], rowx[sigma(v, mm)], acc);
    }
    xc[dd * 65 + l] = fsilu(acc);
  }
  __syncthreads();
  const int lane = tid & 63;
  const int w = __builtin_amdgcn_readfirstlane(tid >> 6);  // wave handles 10 r's
  float acc[10];
#pragma unroll
  for (int rr = 0; rr < 10; ++rr) acc[rr] = 0.f;
  for (int dd = 0; dd < 192; ++dd) {
    float xv = xc[dd * 65 + lane];
#pragma unroll
    for (int rr = 0; rr < 10; ++rr) {
      int r = w * 10 + rr;
      if (r < 38) acc[rr] = fmaf(xv, xp_s[r * 192 + dd], acc[rr]);
    }
  }
  const size_t base = (((size_t)(v * 64 + b)) * 512 + (l0 + lane)) * 40;
#pragma unroll
  for (int rr = 0; rr < 10; ++rr) {
    int r = w * 10 + rr;
    if (r < 38) xdbl[base + (r < 6 ? r : r + 2)] = acc[rr];
  }
}

// ---------------- K3a: chunk-local scan (h0=0) + decay products.
__global__ __launch_bounds__(256) void k3a_scan(const float* __restrict__ xz,
    const float* __restrict__ xdbl, ScanParams p, float* __restrict__ osum,
    float* __restrict__ hend, float* __restrict__ pAbuf) {
  __shared__ __align__(16) float xs[192 * 33];
  __shared__ __align__(16) float zs[192 * 33];
  __shared__ __align__(16) float xd[32 * 40];
  const int chunk = blockIdx.x, b = blockIdx.y, v = blockIdx.z;
  const float* cw = p.cw[v]; const float* cb = p.cb[v];
  const float* dtw = p.dtw[v]; const float* dtb = p.dtb[v];
  const float* al = p.al[v]; const float* dp = p.dp[v];
  const int tid = threadIdx.x;
  float A2[16], h[16], pA[16], dtwr[6], dtbd = 0.f, Dpd = 0.f;
  if (tid < 192) {
#pragma unroll
    for (int s = 0; s < 16; ++s) { A2[s] = -__expf(al[tid * 16 + s]); h[s] = 0.f; pA[s] = 1.f; }
#pragma unroll
    for (int r = 0; r < 6; ++r) dtwr[r] = dtw[tid * 6 + r];
    dtbd = dtb[tid]; Dpd = dp[tid];
  }
  const float* rowx_base = xz + (size_t)b * 384 * 512;
  const size_t xdbase = (((size_t)(v * 64 + b)) * 512) * 40;
  for (int sub = 0; sub < 2; ++sub) {
    const int l0 = chunk * 64 + sub * 32;
    __syncthreads();
    for (int m = tid; m < 192 * 32; m += 256) {
      int dd = m >> 5, l = m & 31;
      const float* rowx = rowx_base + (size_t)dd * 512;
      const float* rowz = rowx_base + (size_t)(192 + dd) * 512;
      float acc = cb[dd];
#pragma unroll
      for (int j = 0; j < 4; ++j) {
        int mm = l0 + l - 3 + j;
        if (mm >= 0) acc = fmaf(cw[dd * 4 + j], rowx[sigma(v, mm)], acc);
      }
      xs[dd * 33 + l] = fsilu(acc);
      zs[dd * 33 + l] = rowz[sigma(v, l0 + l)];
    }
    for (int m = tid; m < 32 * 40; m += 256) xd[m] = xdbl[xdbase + (size_t)l0 * 40 + m];
    __syncthreads();
    if (tid < 192) {
      for (int l = 0; l < 32; ++l) {
        const float* row = xd + l * 40;
        float dtv = dtbd;
#pragma unroll
        for (int r = 0; r < 6; ++r) dtv = fmaf(row[r], dtwr[r], dtv);
        float delta = (dtv > 15.f) ? dtv : __logf(1.f + __expf(dtv));
        float Bv[16], Cv[16];
#pragma unroll
        for (int q = 0; q < 4; ++q) {
          float4 tb = ((const float4*)(row + 8))[q];
          float4 tc = ((const float4*)(row + 24))[q];
          Bv[4 * q] = tb.x; Bv[4 * q + 1] = tb.y; Bv[4 * q + 2] = tb.z; Bv[4 * q + 3] = tb.w;
          Cv[4 * q] = tc.x; Cv[4 * q + 1] = tc.y; Cv[4 * q + 2] = tc.z; Cv[4 * q + 3] = tc.w;
        }
        float u = xs[tid * 33 + l];
        float du = delta * u;
        float y = 0.f;
#pragma unroll
        for (int s = 0; s < 16; ++s) {
          float a = __expf(delta * A2[s]);
          h[s] = fmaf(h[s], a, du * Bv[s]);
          pA[s] *= a;
          y = fmaf(h[s], Cv[s], y);
        }
        float zv = zs[tid * 33 + l];
        float res = (y + Dpd * u) * fsilu(zv);
        unsafeAtomicAdd(&osum[((size_t)b * 512 + sigma(v, chunk * 64 + sub * 32 + l)) * 192 + tid], res);
      }
    }
  }
  if (tid < 192) {
    const size_t base = ((((size_t)(v * 64 + b)) * NCH + chunk) * 192 + tid) * 16;
#pragma unroll
    for (int q = 0; q < 4; ++q) {
      *(float4*)&hend[base + 4 * q] = make_float4(h[4 * q], h[4 * q + 1], h[4 * q + 2], h[4 * q + 3]);
      *(float4*)&pAbuf[base + 4 * q] = make_float4(pA[4 * q], pA[4 * q + 1], pA[4 * q + 2], pA[4 * q + 3]);
    }
  }
}

// ---------------- K3b: combine chunk states; hend[c] is overwritten with Hin[c].
__global__ __launch_bounds__(256) void k3b_combine(float* __restrict__ hend,
    const float* __restrict__ pAbuf) {
  const int g = blockIdx.x * 256 + threadIdx.x;   // 3*64*192*16 = 589824 threads
  const int s = g & 15;
  const int rest = g >> 4;
  const int d = rest % 192;
  const int bb = rest / 192;                      // v*64+b
  const size_t base0 = (((size_t)bb * NCH) * 192 + d) * 16 + s;
  float H = 0.f;
#pragma unroll
  for (int c = 0; c < NCH; ++c) {
    const size_t idx = base0 + (size_t)c * 192 * 16;
    float he = hend[idx];
    float pa = pAbuf[idx];
    hend[idx] = H;
    H = fmaf(pa, H, he);
  }
}

// ---------------- K3c: cross-chunk correction: y += C_t . (cumA_t ⊙ Hin), gated by silu(z)
__global__ __launch_bounds__(256) void k3c_fix(const float* __restrict__ xz,
    const float* __restrict__ xdbl, ScanParams p, const float* __restrict__ hend,
    float* __restrict__ osum) {
  __shared__ __align__(16) float zs[192 * 65];
  __shared__ __align__(16) float xd[64 * 40];
  const int chunk = blockIdx.x + 1, b = blockIdx.y, v = blockIdx.z;
  const float* dtw = p.dtw[v]; const float* dtb = p.dtb[v]; const float* al = p.al[v];
  const int tid = threadIdx.x;
  const int l0 = chunk * 64;
  float A2[16], g[16], dtwr[6], dtbd = 0.f;
  if (tid < 192) {
#pragma unroll
    for (int s = 0; s < 16; ++s) A2[s] = -__expf(al[tid * 16 + s]);
    const size_t base = ((((size_t)(v * 64 + b)) * NCH + chunk) * 192 + tid) * 16;
#pragma unroll
    for (int q = 0; q < 4; ++q) {
      float4 hv = *(const float4*)&hend[base + 4 * q];
      g[4 * q] = hv.x; g[4 * q + 1] = hv.y; g[4 * q + 2] = hv.z; g[4 * q + 3] = hv.w;
    }
#pragma unroll
    for (int r = 0; r < 6; ++r) dtwr[r] = dtw[tid * 6 + r];
    dtbd = dtb[tid];
  }
  const float* rowz_base = xz + (size_t)b * 384 * 512 + (size_t)192 * 512;
  const size_t xdbase = (((size_t)(v * 64 + b)) * 512 + l0) * 40;
  for (int m = tid; m < 192 * 64; m += 256) {
    int dd = m >> 6, l = m & 63;
    zs[dd * 65 + l] = rowz_base[(size_t)dd * 512 + sigma(v, l0 + l)];
  }
  for (int m = tid; m < 64 * 40; m += 256) xd[m] = xdbl[xdbase + m];
  __syncthreads();
  if (tid < 192) {
    for (int l = 0; l < 64; ++l) {
      const float* row = xd + l * 40;
      float dtv = dtbd;
#pragma unroll
      for (int r = 0; r < 6; ++r) dtv = fmaf(row[r], dtwr[r], dtv);
      float delta = (dtv > 15.f) ? dtv : __logf(1.f + __expf(dtv));
      float ycorr = 0.f;
#pragma unroll
      for (int q = 0; q < 4; ++q) {
        float4 tc = ((const float4*)(row + 24))[q];
        float a0 = __expf(delta * A2[4 * q + 0]); g[4 * q + 0] *= a0;
        float a1 = __expf(delta * A2[4 * q + 1]); g[4 * q + 1] *= a1;
        float a2 = __expf(delta * A2[4 * q + 2]); g[4 * q + 2] *= a2;
        float a3 = __expf(delta * A2[4 * q + 3]); g[4 * q + 3] *= a3;
        ycorr = fmaf(g[4 * q + 0], tc.x, ycorr);
        ycorr = fmaf(g[4 * q + 1], tc.y, ycorr);
        ycorr = fmaf(g[4 * q + 2], tc.z, ycorr);
        ycorr = fmaf(g[4 * q + 3], tc.w, ycorr);
      }
      float zv = zs[tid * 65 + l];
      float res = ycorr * fsilu(zv);
      unsafeAtomicAdd(&osum[((size_t)b * 512 + sigma(v, l0 + l)) * 192 + tid], res);
    }
  }
}

// ---------------- K4: out_proj + window_reverse + residual + channel sums
__global__ __launch_bounds__(256) void k4_outproj(const float* __restrict__ osum,
    const float* __restrict__ wop, const float* __restrict__ x,
    float* __restrict__ out, float* __restrict__ csum) {
  __shared__ float yt[64 * 193];
  __shared__ float wT[192 * 34];      // [dd][e_local], tile of 32 e
  __shared__ float csum_s[96];
  const int tid = threadIdx.x;
  const int t0 = blockIdx.x * 64;
  const int b = t0 >> 9, l0 = t0 & 511;
  if (tid < 96) csum_s[tid] = 0.f;
  for (int m = tid; m < 64 * 192; m += 256) {
    int tt = m / 192, dd = m - tt * 192;
    yt[tt * 193 + dd] = osum[((size_t)b * 512 + l0 + tt) * 192 + dd];
  }
  const int hb = b >> 4, wb = (b >> 2) & 3, db = b & 3;
  const int t0l = (tid & 15) * 4;
  const int e0 = (tid >> 4) * 2;
  int sp[4];
#pragma unroll
  for (int j = 0; j < 4; ++j) {
    int l = l0 + t0l + j;
    int i = l >> 6, jj = (l >> 3) & 7, k = l & 7;
    sp[j] = (hb * 8 + i) * 1024 + (wb * 8 + jj) * 32 + (db * 8 + k);
  }
  for (int et = 0; et < 3; ++et) {
    __syncthreads();
    for (int m = tid; m < 192 * 32; m += 256) {
      int dd = m >> 5, e_l = m & 31;
      wT[dd * 34 + e_l] = wop[(et * 32 + e_l) * 192 + dd];
    }
    __syncthreads();
    float acc[4][2];
#pragma unroll
    for (int j = 0; j < 4; ++j) { acc[j][0] = 0.f; acc[j][1] = 0.f; }
    for (int dd = 0; dd < 192; ++dd) {
      float2 bv = *(const float2*)&wT[dd * 34 + e0];
      float a0 = yt[(t0l + 0) * 193 + dd], a1 = yt[(t0l + 1) * 193 + dd];
      float a2 = yt[(t0l + 2) * 193 + dd], a3 = yt[(t0l + 3) * 193 + dd];
      acc[0][0] = fmaf(a0, bv.x, acc[0][0]); acc[0][1] = fmaf(a0, bv.y, acc[0][1]);
      acc[1][0] = fmaf(a1, bv.x, acc[1][0]); acc[1][1] = fmaf(a1, bv.y, acc[1][1]);
      acc[2][0] = fmaf(a2, bv.x, acc[2][0]); acc[2][1] = fmaf(a2, bv.y, acc[2][1]);
      acc[3][0] = fmaf(a3, bv.x, acc[3][0]); acc[3][1] = fmaf(a3, bv.y, acc[3][1]);
    }
    float part[2] = {0.f, 0.f};
#pragma unroll
    for (int i = 0; i < 2; ++i) {
      const int c = et * 32 + e0 + i;
#pragma unroll
      for (int j = 0; j < 4; ++j) {
        float val = acc[j][i] + x[c * 32768 + sp[j]];
        out[c * 32768 + sp[j]] = val;
        part[i] += val;
      }
      atomicAdd(&csum_s[c], part[i]);
    }
  }
  __syncthreads();
  if (tid < 96) unsafeAtomicAdd(&csum[tid], csum_s[tid]);
}

// ---------------- K5: ECA gate (k=3 conv over channel means + sigmoid), in-place scale
__global__ __launch_bounds__(256) void k5_eca(float* __restrict__ out,
    const float* __restrict__ csum, const float* __restrict__ ew) {
  const int idx = blockIdx.x * 256 + threadIdx.x;   // float4 index, 786432 total
  const int c = (idx * 4) >> 15;
  const float inv = 1.f / 32768.f;
  float m0 = csum[c] * inv;
  float mm = (c > 0) ? csum[c - 1] * inv : 0.f;
  float mp = (c < 95) ? csum[c + 1] * inv : 0.f;
  float gate = fsigmoid(ew[0] * mm + ew[1] * m0 + ew[2] * mp);
  float4 vv = ((const float4*)out)[idx];
  vv.x *= gate; vv.y *= gate; vv.z *= gate; vv.w *= gate;
  ((float4*)out)[idx] = vv;
}

extern "C" void kernel_launch(void* const* d_in, const int* in_sizes, int n_in,
                              void* d_out, int out_size, void* d_ws, size_t ws_size,
                              hipStream_t stream) {
  const float* x   = (const float*)d_in[0];
  const float* lnw = (const float*)d_in[1];
  const float* lnb = (const float*)d_in[2];
  const float* wip = (const float*)d_in[3];
  const float* wop = (const float*)d_in[4];
  const float* ew  = (const float*)d_in[5];
  ScanParams p;
  for (int v = 0; v < 3; ++v) {
    const int base = 6 + 7 * v;
    p.cw[v]  = (const float*)d_in[base + 0];
    p.cb[v]  = (const float*)d_in[base + 1];
    p.xp[v]  = (const float*)d_in[base + 2];
    p.dtw[v] = (const float*)d_in[base + 3];
    p.dtb[v] = (const float*)d_in[base + 4];
    p.al[v]  = (const float*)d_in[base + 5];
    p.dp[v]  = (const float*)d_in[base + 6];
  }
  float* ws   = (float*)d_ws;
  float* xz   = ws;                       // 12,582,912
  float* osum = ws + 12582912;            //  6,291,456
  float* xdbl = ws + 18874368;            //  3,932,160
  float* csum = ws + 22806528;            //         96 (pad to 128)
  float* hend = ws + 22806656;            //  2,359,296
  float* pAbf = ws + 25165952;            //  2,359,296
  float* outf = (float*)d_out;

  hipMemsetAsync(osum, 0, (size_t)6291456 * 4, stream);
  hipMemsetAsync(csum, 0, 96 * 4, stream);
  k1_ln_inproj<<<512, 256, 0, stream>>>(x, lnw, lnb, wip, xz);
  k2_conv_xdbl<<<dim3(8, 64, 3), 256, 0, stream>>>(xz, p, xdbl);
  k3a_scan<<<dim3(NCH, 64, 3), 256, 0, stream>>>(xz, xdbl, p, osum, hend, pAbf);
  k3b_combine<<<2304, 256, 0, stream>>>(hend, pAbf);
  k3c_fix<<<dim3(NCH - 1, 64, 3), 256, 0, stream>>>(xz, xdbl, p, hend, osum);
  k4_outproj<<<512, 256, 0, stream>>>(osum, wop, x, outf, csum);
  k5_eca<<<3072, 256, 0, stream>>>(outf, csum, ew);
}

// Round 3
// 800.492 us; speedup vs baseline: 1.7674x; 1.3083x over previous
//
#include <hip/hip_runtime.h>
#include <hip/hip_bf16.h>

// MambaLayer fused pipeline, fp32, chunk-parallel selective scan.
// xz layout: (b, l, e) with e minor (coalesced channel-row reads for all permutations).
// silu(z) gating deferred to k4 (common across the 3 scan directions).
// ws layout (floats):
//   xz   [64*512*384]            = 12,582,912
//   osum [64*512*192]            =  6,291,456   (pre-gate sum of 3 directions)
//   xdbl [3*64*512*40]           =  3,932,160
//   csum [96] (pad 128)
//   hend [3*64*8*192*16]         =  2,359,296   (after k3b: Hin per chunk)
//   pA   [3*64*8*192*16]         =  2,359,296

#define DEV __device__ __forceinline__
#define NCH 8           // scan chunks (L=512 -> 64 steps per chunk)

DEV float fsigmoid(float x) { return 1.f / (1.f + __expf(-x)); }
DEV float fsilu(float x) { return x * fsigmoid(x); }

// position m in the permuted (scan) domain -> source index in original L domain.
DEV int sigma(int v, int m) {
  if (v == 0) return m;
  if (v == 1) return 511 - m;
  return ((m & 7) << 6) | (m >> 3);   // v3 inter-slice: m=i*8+j -> j*64+i
}

struct ScanParams {
  const float* cw[3]; const float* cb[3]; const float* xp[3];
  const float* dtw[3]; const float* dtb[3]; const float* al[3]; const float* dp[3];
};

// ---------------- K1: window_partition + LayerNorm + in_proj GEMM -> xz (b,l,e)
__global__ __launch_bounds__(256) void k1_ln_inproj(const float* __restrict__ x,
    const float* __restrict__ lnw, const float* __restrict__ lnb,
    const float* __restrict__ wip, float* __restrict__ xz) {
  __shared__ float xt[64 * 97];       // [token][chan]
  __shared__ float wt[96 * 68];       // [chan][e_local]
  __shared__ float mu_s[64], rs_s[64];
  const int tid = threadIdx.x;
  const int t0 = blockIdx.x * 64;     // 64 tokens per block, 512 blocks
  const int b = t0 >> 9, l0 = t0 & 511;
  const int hb = b >> 4, wb = (b >> 2) & 3, db = b & 3;
  for (int m = tid; m < 96 * 64; m += 256) {
    int c = m >> 6, tt = m & 63;
    int l = l0 + tt;
    int i = l >> 6, j = (l >> 3) & 7, k = l & 7;
    xt[tt * 97 + c] = x[c * 32768 + (hb * 8 + i) * 1024 + (wb * 8 + j) * 32 + (db * 8 + k)];
  }
  __syncthreads();
  if (tid < 64) {
    float s = 0.f;
    for (int c = 0; c < 96; ++c) s += xt[tid * 97 + c];
    float mu = s * (1.f / 96.f);
    float s2 = 0.f;
    for (int c = 0; c < 96; ++c) { float dv = xt[tid * 97 + c] - mu; s2 = fmaf(dv, dv, s2); }
    mu_s[tid] = mu;
    rs_s[tid] = rsqrtf(s2 * (1.f / 96.f) + 1e-5f);
  }
  __syncthreads();
  for (int m = tid; m < 96 * 64; m += 256) {
    int c = m >> 6, tt = m & 63;
    xt[tt * 97 + c] = (xt[tt * 97 + c] - mu_s[tt]) * rs_s[tt] * lnw[c] + lnb[c];
  }
  __syncthreads();
  // GEMM: 64 tokens x 384 outputs, e-tiles of 64. thread = 4 tokens x 4 e.
  const int t0l = (tid & 15) * 4;
  const int e0 = (tid >> 4) * 4;
  const size_t obase = (size_t)b * 512 * 384;
  for (int et = 0; et < 6; ++et) {
    for (int m = tid; m < 64 * 96; m += 256) {
      int e_l = m / 96, c = m - e_l * 96;
      wt[c * 68 + e_l] = wip[(et * 64 + e_l) * 96 + c];
    }
    __syncthreads();
    float acc[4][4];
#pragma unroll
    for (int j = 0; j < 4; ++j)
#pragma unroll
      for (int i = 0; i < 4; ++i) acc[j][i] = 0.f;
    for (int c = 0; c < 96; ++c) {
      float4 bv = *(const float4*)&wt[c * 68 + e0];
      float a0 = xt[(t0l + 0) * 97 + c], a1 = xt[(t0l + 1) * 97 + c];
      float a2 = xt[(t0l + 2) * 97 + c], a3 = xt[(t0l + 3) * 97 + c];
      acc[0][0] = fmaf(a0, bv.x, acc[0][0]); acc[0][1] = fmaf(a0, bv.y, acc[0][1]);
      acc[0][2] = fmaf(a0, bv.z, acc[0][2]); acc[0][3] = fmaf(a0, bv.w, acc[0][3]);
      acc[1][0] = fmaf(a1, bv.x, acc[1][0]); acc[1][1] = fmaf(a1, bv.y, acc[1][1]);
      acc[1][2] = fmaf(a1, bv.z, acc[1][2]); acc[1][3] = fmaf(a1, bv.w, acc[1][3]);
      acc[2][0] = fmaf(a2, bv.x, acc[2][0]); acc[2][1] = fmaf(a2, bv.y, acc[2][1]);
      acc[2][2] = fmaf(a2, bv.z, acc[2][2]); acc[2][3] = fmaf(a2, bv.w, acc[2][3]);
      acc[3][0] = fmaf(a3, bv.x, acc[3][0]); acc[3][1] = fmaf(a3, bv.y, acc[3][1]);
      acc[3][2] = fmaf(a3, bv.z, acc[3][2]); acc[3][3] = fmaf(a3, bv.w, acc[3][3]);
    }
#pragma unroll
    for (int j = 0; j < 4; ++j) {
      float4 o = make_float4(acc[j][0], acc[j][1], acc[j][2], acc[j][3]);
      *(float4*)&xz[obase + (size_t)(l0 + t0l + j) * 384 + (et * 64 + e0)] = o;
    }
    __syncthreads();
  }
}

// ---------------- K3a: chunk-local scan (h0=0) + fused x_dbl projection.
// xdbl slot layout per token: dt[0..5], (pad 6..7), B[8..23], C[24..39]
__global__ __launch_bounds__(256) void k3a_scan(const float* __restrict__ xz,
    ScanParams p, float* __restrict__ osum, float* __restrict__ xdbl,
    float* __restrict__ hend, float* __restrict__ pAbuf) {
  __shared__ __align__(16) float xs[32 * 193];   // [l][dd] stride 193 (conflict-free both ways)
  __shared__ __align__(16) float xd[32 * 40];
  __shared__ float xp_s[38 * 192];
  const int chunk = blockIdx.x, b = blockIdx.y, v = blockIdx.z;
  const float* cw = p.cw[v]; const float* cb = p.cb[v];
  const float* dtw = p.dtw[v]; const float* dtb = p.dtb[v];
  const float* al = p.al[v]; const float* dp = p.dp[v];
  const int tid = threadIdx.x;
  for (int m = tid; m < 38 * 192; m += 256) xp_s[m] = p.xp[v][m];
  float A2[16], h[16], dtwr[6], dtbd = 0.f, Dpd = 0.f, sdelta = 0.f;
  if (tid < 192) {
#pragma unroll
    for (int s = 0; s < 16; ++s) { A2[s] = -__expf(al[tid * 16 + s]); h[s] = 0.f; }
#pragma unroll
    for (int r = 0; r < 6; ++r) dtwr[r] = dtw[tid * 6 + r];
    dtbd = dtb[tid]; Dpd = dp[tid];
  }
  const float* xzb = xz + (size_t)b * 512 * 384;
  const int lane5 = tid & 31;
  const int r0 = (tid >> 6) * 10 + ((tid >> 5) & 1) * 5;
  for (int sub = 0; sub < 2; ++sub) {
    const int l0 = chunk * 64 + sub * 32;
    __syncthreads();
    // stage conv'd+silu'd x rows (coalesced along dd for every permutation)
    for (int m = tid; m < 32 * 192; m += 256) {
      int l = m / 192, dd = m - l * 192;
      float acc = cb[dd];
#pragma unroll
      for (int j = 0; j < 4; ++j) {
        int mm = l0 + l - 3 + j;
        if (mm >= 0) acc = fmaf(cw[dd * 4 + j], xzb[(size_t)sigma(v, mm) * 384 + dd], acc);
      }
      xs[l * 193 + dd] = fsilu(acc);
    }
    __syncthreads();
    // x_dbl tile: 32 tokens x 38 r, reduce over 192 dd. lane=token, r split 8x5.
    {
      float a5[5] = {0.f, 0.f, 0.f, 0.f, 0.f};
      for (int dd = 0; dd < 192; ++dd) {
        float xv = xs[lane5 * 193 + dd];
#pragma unroll
        for (int rr = 0; rr < 5; ++rr) {
          int r = r0 + rr;
          if (r < 38) a5[rr] = fmaf(xv, xp_s[r * 192 + dd], a5[rr]);
        }
      }
      const size_t gb = (((size_t)(v * 64 + b)) * 512 + (l0 + lane5)) * 40;
#pragma unroll
      for (int rr = 0; rr < 5; ++rr) {
        int r = r0 + rr;
        if (r < 38) {
          int slot = (r < 6) ? r : r + 2;
          xd[lane5 * 40 + slot] = a5[rr];
          xdbl[gb + slot] = a5[rr];
        }
      }
    }
    __syncthreads();
    if (tid < 192) {
      for (int l = 0; l < 32; ++l) {
        const float* row = xd + l * 40;   // uniform per step -> LDS broadcast
        float dtv = dtbd;
#pragma unroll
        for (int r = 0; r < 6; ++r) dtv = fmaf(row[r], dtwr[r], dtv);
        float delta = (dtv > 15.f) ? dtv : __logf(1.f + __expf(dtv));
        sdelta += delta;
        float Bv[16], Cv[16];
#pragma unroll
        for (int q = 0; q < 4; ++q) {
          float4 tb = ((const float4*)(row + 8))[q];
          float4 tc = ((const float4*)(row + 24))[q];
          Bv[4 * q] = tb.x; Bv[4 * q + 1] = tb.y; Bv[4 * q + 2] = tb.z; Bv[4 * q + 3] = tb.w;
          Cv[4 * q] = tc.x; Cv[4 * q + 1] = tc.y; Cv[4 * q + 2] = tc.z; Cv[4 * q + 3] = tc.w;
        }
        float u = xs[l * 193 + tid];
        float du = delta * u;
        float y = 0.f;
#pragma unroll
        for (int s = 0; s < 16; ++s) {
          float a = __expf(delta * A2[s]);
          h[s] = fmaf(h[s], a, du * Bv[s]);
          y = fmaf(h[s], Cv[s], y);
        }
        float res = fmaf(Dpd, u, y);     // gate applied later in k4
        unsafeAtomicAdd(&osum[((size_t)b * 512 + sigma(v, l0 + l)) * 192 + tid], res);
      }
    }
  }
  if (tid < 192) {
    const size_t base = ((((size_t)(v * 64 + b)) * NCH + chunk) * 192 + tid) * 16;
#pragma unroll
    for (int q = 0; q < 4; ++q) {
      *(float4*)&hend[base + 4 * q] = make_float4(h[4 * q], h[4 * q + 1], h[4 * q + 2], h[4 * q + 3]);
      // decay product over the chunk: exp(A2[s] * sum(delta)) — exact, one rounding
      *(float4*)&pAbuf[base + 4 * q] = make_float4(
          __expf(A2[4 * q] * sdelta), __expf(A2[4 * q + 1] * sdelta),
          __expf(A2[4 * q + 2] * sdelta), __expf(A2[4 * q + 3] * sdelta));
    }
  }
}

// ---------------- K3b: combine chunk states; hend[c] is overwritten with Hin[c].
__global__ __launch_bounds__(256) void k3b_combine(float* __restrict__ hend,
    const float* __restrict__ pAbuf) {
  const int g = blockIdx.x * 256 + threadIdx.x;   // 3*64*192*16 = 589824 threads
  const int s = g & 15;
  const int rest = g >> 4;
  const int d = rest % 192;
  const int bb = rest / 192;                      // v*64+b
  const size_t base0 = (((size_t)bb * NCH) * 192 + d) * 16 + s;
  float H = 0.f;
#pragma unroll
  for (int c = 0; c < NCH; ++c) {
    const size_t idx = base0 + (size_t)c * 192 * 16;
    float he = hend[idx];
    float pa = pAbuf[idx];
    hend[idx] = H;
    H = fmaf(pa, H, he);
  }
}

// ---------------- K3c: cross-chunk correction: y += C_t . (exp(A2*cumd) ⊙ Hin)
__global__ __launch_bounds__(256) void k3c_fix(const float* __restrict__ xdbl,
    ScanParams p, const float* __restrict__ hend, float* __restrict__ osum) {
  __shared__ __align__(16) float xd[64 * 40];
  const int chunk = blockIdx.x + 1, b = blockIdx.y, v = blockIdx.z;
  const float* dtw = p.dtw[v]; const float* dtb = p.dtb[v]; const float* al = p.al[v];
  const int tid = threadIdx.x;
  const int l0 = chunk * 64;
  float A2[16], g0[16], dtwr[6], dtbd = 0.f, cumd = 0.f;
  if (tid < 192) {
#pragma unroll
    for (int s = 0; s < 16; ++s) A2[s] = -__expf(al[tid * 16 + s]);
    const size_t base = ((((size_t)(v * 64 + b)) * NCH + chunk) * 192 + tid) * 16;
#pragma unroll
    for (int q = 0; q < 4; ++q) {
      float4 hv = *(const float4*)&hend[base + 4 * q];
      g0[4 * q] = hv.x; g0[4 * q + 1] = hv.y; g0[4 * q + 2] = hv.z; g0[4 * q + 3] = hv.w;
    }
#pragma unroll
    for (int r = 0; r < 6; ++r) dtwr[r] = dtw[tid * 6 + r];
    dtbd = dtb[tid];
  }
  const size_t xdbase = (((size_t)(v * 64 + b)) * 512 + l0) * 40;
  for (int m = tid; m < 64 * 40; m += 256) xd[m] = xdbl[xdbase + m];
  __syncthreads();
  if (tid < 192) {
    for (int l = 0; l < 64; ++l) {
      const float* row = xd + l * 40;
      float dtv = dtbd;
#pragma unroll
      for (int r = 0; r < 6; ++r) dtv = fmaf(row[r], dtwr[r], dtv);
      float delta = (dtv > 15.f) ? dtv : __logf(1.f + __expf(dtv));
      cumd += delta;
      float yc = 0.f;
#pragma unroll
      for (int q = 0; q < 4; ++q) {
        float4 tc = ((const float4*)(row + 24))[q];
        yc = fmaf(g0[4 * q + 0] * __expf(A2[4 * q + 0] * cumd), tc.x, yc);
        yc = fmaf(g0[4 * q + 1] * __expf(A2[4 * q + 1] * cumd), tc.y, yc);
        yc = fmaf(g0[4 * q + 2] * __expf(A2[4 * q + 2] * cumd), tc.z, yc);
        yc = fmaf(g0[4 * q + 3] * __expf(A2[4 * q + 3] * cumd), tc.w, yc);
      }
      unsafeAtomicAdd(&osum[((size_t)b * 512 + sigma(v, l0 + l)) * 192 + tid], yc);
    }
  }
}

// ---------------- K4: silu(z) gate + out_proj + window_reverse + residual + channel sums
__global__ __launch_bounds__(256) void k4_outproj(const float* __restrict__ osum,
    const float* __restrict__ xz, const float* __restrict__ wop,
    const float* __restrict__ x, float* __restrict__ out, float* __restrict__ csum) {
  __shared__ float yt[64 * 193];
  __shared__ float wT[192 * 34];
  __shared__ float csum_s[96];
  const int tid = threadIdx.x;
  const int t0 = blockIdx.x * 64;
  const int b = t0 >> 9, l0 = t0 & 511;
  if (tid < 96) csum_s[tid] = 0.f;
  for (int m = tid; m < 64 * 192; m += 256) {
    int tt = m / 192, dd = m - tt * 192;
    float zv = xz[((size_t)b * 512 + l0 + tt) * 384 + 192 + dd];
    yt[tt * 193 + dd] = osum[((size_t)b * 512 + l0 + tt) * 192 + dd] * fsilu(zv);
  }
  const int hb = b >> 4, wb = (b >> 2) & 3, db = b & 3;
  const int t0l = (tid & 15) * 4;
  const int e0 = (tid >> 4) * 2;
  int sp[4];
#pragma unroll
  for (int j = 0; j < 4; ++j) {
    int l = l0 + t0l + j;
    int i = l >> 6, jj = (l >> 3) & 7, k = l & 7;
    sp[j] = (hb * 8 + i) * 1024 + (wb * 8 + jj) * 32 + (db * 8 + k);
  }
  for (int et = 0; et < 3; ++et) {
    __syncthreads();
    for (int m = tid; m < 192 * 32; m += 256) {
      int dd = m >> 5, e_l = m & 31;
      wT[dd * 34 + e_l] = wop[(et * 32 + e_l) * 192 + dd];
    }
    __syncthreads();
    float acc[4][2];
#pragma unroll
    for (int j = 0; j < 4; ++j) { acc[j][0] = 0.f; acc[j][1] = 0.f; }
    for (int dd = 0; dd < 192; ++dd) {
      float2 bv = *(const float2*)&wT[dd * 34 + e0];
      float a0 = yt[(t0l + 0) * 193 + dd], a1 = yt[(t0l + 1) * 193 + dd];
      float a2 = yt[(t0l + 2) * 193 + dd], a3 = yt[(t0l + 3) * 193 + dd];
      acc[0][0] = fmaf(a0, bv.x, acc[0][0]); acc[0][1] = fmaf(a0, bv.y, acc[0][1]);
      acc[1][0] = fmaf(a1, bv.x, acc[1][0]); acc[1][1] = fmaf(a1, bv.y, acc[1][1]);
      acc[2][0] = fmaf(a2, bv.x, acc[2][0]); acc[2][1] = fmaf(a2, bv.y, acc[2][1]);
      acc[3][0] = fmaf(a3, bv.x, acc[3][0]); acc[3][1] = fmaf(a3, bv.y, acc[3][1]);
    }
#pragma unroll
    for (int i = 0; i < 2; ++i) {
      const int c = et * 32 + e0 + i;
      float part = 0.f;
#pragma unroll
      for (int j = 0; j < 4; ++j) {
        float val = acc[j][i] + x[c * 32768 + sp[j]];
        out[c * 32768 + sp[j]] = val;
        part += val;
      }
      atomicAdd(&csum_s[c], part);
    }
  }
  __syncthreads();
  if (tid < 96) unsafeAtomicAdd(&csum[tid], csum_s[tid]);
}

// ---------------- K5: ECA gate (k=3 conv over channel means + sigmoid), in-place scale
__global__ __launch_bounds__(256) void k5_eca(float* __restrict__ out,
    const float* __restrict__ csum, const float* __restrict__ ew) {
  const int idx = blockIdx.x * 256 + threadIdx.x;   // float4 index, 786432 total
  const int c = (idx * 4) >> 15;
  const float inv = 1.f / 32768.f;
  float m0 = csum[c] * inv;
  float mm = (c > 0) ? csum[c - 1] * inv : 0.f;
  float mp = (c < 95) ? csum[c + 1] * inv : 0.f;
  float gate = fsigmoid(ew[0] * mm + ew[1] * m0 + ew[2] * mp);
  float4 vv = ((const float4*)out)[idx];
  vv.x *= gate; vv.y *= gate; vv.z *= gate; vv.w *= gate;
  ((float4*)out)[idx] = vv;
}

extern "C" void kernel_launch(void* const* d_in, const int* in_sizes, int n_in,
                              void* d_out, int out_size, void* d_ws, size_t ws_size,
                              hipStream_t stream) {
  const float* x   = (const float*)d_in[0];
  const float* lnw = (const float*)d_in[1];
  const float* lnb = (const float*)d_in[2];
  const float* wip = (const float*)d_in[3];
  const float* wop = (const float*)d_in[4];
  const float* ew  = (const float*)d_in[5];
  ScanParams p;
  for (int v = 0; v < 3; ++v) {
    const int base = 6 + 7 * v;
    p.cw[v]  = (const float*)d_in[base + 0];
    p.cb[v]  = (const float*)d_in[base + 1];
    p.xp[v]  = (const float*)d_in[base + 2];
    p.dtw[v] = (const float*)d_in[base + 3];
    p.dtb[v] = (const float*)d_in[base + 4];
    p.al[v]  = (const float*)d_in[base + 5];
    p.dp[v]  = (const float*)d_in[base + 6];
  }
  float* ws   = (float*)d_ws;
  float* xz   = ws;                       // 12,582,912
  float* osum = ws + 12582912;            //  6,291,456
  float* xdbl = ws + 18874368;            //  3,932,160
  float* csum = ws + 22806528;            //  96 (pad 128)
  float* hend = ws + 22806656;            //  2,359,296
  float* pAbf = ws + 25165952;            //  2,359,296
  float* outf = (float*)d_out;

  hipMemsetAsync(osum, 0, (size_t)6291456 * 4, stream);
  hipMemsetAsync(csum, 0, 96 * 4, stream);
  k1_ln_inproj<<<512, 256, 0, stream>>>(x, lnw, lnb, wip, xz);
  k3a_scan<<<dim3(NCH, 64, 3), 256, 0, stream>>>(xz, p, osum, xdbl, hend, pAbf);
  k3b_combine<<<2304, 256, 0, stream>>>(hend, pAbf);
  k3c_fix<<<dim3(NCH - 1, 64, 3), 256, 0, stream>>>(xdbl, p, hend, osum);
  k4_outproj<<<512, 256, 0, stream>>>(osum, xz, wop, x, outf, csum);
  k5_eca<<<3072, 256, 0, stream>>>(outf, csum, ew);
}